// Round 1
// baseline (262.179 us; speedup 1.0000x reference)
//
#include <hip/hip_runtime.h>
#include <hip/hip_bf16.h>

using bf16 = __hip_bfloat16;
using bf16x8 = __attribute__((ext_vector_type(8))) __bf16;
using f32x4 = __attribute__((ext_vector_type(4))) float;

typedef const __attribute__((address_space(1))) void* gas_ptr;
typedef __attribute__((address_space(3))) void* las_ptr;
#define LOAD_LDS16(g, l) \
    __builtin_amdgcn_global_load_lds((gas_ptr)(const void*)(g), (las_ptr)(void*)(l), 16, 0, 0)

#define LOG_DIM 11
#define BDIM 2048           // butterfly / hidden dim
#define NFEAT 2048          // in/out features
#define BATCH 16384

// ---------------------------------------------------------------------------
// 1) fp32 -> bf16 convert, 8 elems/thread, vectorized
// ---------------------------------------------------------------------------
__global__ __launch_bounds__(256) void cvt_fp32_bf16(const float* __restrict__ in,
                                                     bf16* __restrict__ out) {
    size_t i = ((size_t)blockIdx.x * 256 + threadIdx.x) * 8;
    float4 v0 = *(const float4*)(in + i);
    float4 v1 = *(const float4*)(in + i + 4);
    union { bf16 h[8]; int4 v; } u;
    u.h[0] = __float2bfloat16(v0.x); u.h[1] = __float2bfloat16(v0.y);
    u.h[2] = __float2bfloat16(v0.z); u.h[3] = __float2bfloat16(v0.w);
    u.h[4] = __float2bfloat16(v1.x); u.h[5] = __float2bfloat16(v1.y);
    u.h[6] = __float2bfloat16(v1.z); u.h[7] = __float2bfloat16(v1.w);
    *(int4*)(out + i) = u.v;
}

// ---------------------------------------------------------------------------
// 2) WoutB[o,:] = W_out[o,:] * B   (row-vector times butterfly matrix)
//    = apply transposed rotations in REVERSE level order:
//      top = a*x0 - b*x1 ; bot = b*x0 + a*x1
//    One row (2048 fp32) per block in LDS. Output bf16.
// ---------------------------------------------------------------------------
__global__ __launch_bounds__(256) void butterfly_wout(const float* __restrict__ W,
                                                      const float* __restrict__ a_pad,
                                                      const float* __restrict__ b_pad,
                                                      bf16* __restrict__ out) {
    __shared__ float v[BDIM];
    const int o = blockIdx.x;
    const int t = threadIdx.x;
    const float* row = W + (size_t)o * BDIM;
    for (int i = t; i < BDIM / 4; i += 256)
        ((float4*)v)[i] = ((const float4*)row)[i];
    __syncthreads();
    for (int l = LOG_DIM - 1; l >= 0; --l) {
        const int bs = 1 << l;
        #pragma unroll
        for (int pp = 0; pp < 4; ++pp) {
            int p = t + pp * 256;               // pair index 0..1023
            int j = p >> l;                     // rotation-block index
            int s = p & (bs - 1);
            int i0 = (j << (l + 1)) | s;
            int i1 = i0 + bs;
            float a = a_pad[l * (BDIM / 2) + j];
            float b = b_pad[l * (BDIM / 2) + j];
            float x0 = v[i0], x1 = v[i1];
            v[i0] = a * x0 - b * x1;
            v[i1] = b * x0 + a * x1;
        }
        __syncthreads();
    }
    union { bf16 h[8]; int4 vv; } u;
    #pragma unroll
    for (int j = 0; j < 8; ++j) u.h[j] = __float2bfloat16(v[t * 8 + j]);
    *(int4*)(out + (size_t)o * BDIM + t * 8) = u.vv;
}

// ---------------------------------------------------------------------------
// 3) WinT[i,k] = W_in[k,i], fp32 -> bf16 (gives B^T layout for GEMM_M)
// ---------------------------------------------------------------------------
__global__ __launch_bounds__(256) void transpose_cvt(const float* __restrict__ in,
                                                     bf16* __restrict__ out) {
    __shared__ float tile[32][33];
    const int bx = blockIdx.x, by = blockIdx.y;
    const int tx = threadIdx.x & 31, ty = threadIdx.x >> 5;
    #pragma unroll
    for (int r = ty; r < 32; r += 8)
        tile[r][tx] = in[(size_t)(by * 32 + r) * NFEAT + bx * 32 + tx];
    __syncthreads();
    #pragma unroll
    for (int r = ty; r < 32; r += 8)
        out[(size_t)(bx * 32 + r) * NFEAT + by * 32 + tx] = __float2bfloat16(tile[tx][r]);
}

// ---------------------------------------------------------------------------
// 4) bf16 GEMM, B^T layout: C[m,n] = sum_k A[m,k] * Bt[n,k]  (+bias[n])
//    m97 structure: 128x128 tile, BK=32, 4 waves (2x2), 4x4 16x16x32 MFMA
//    frags per wave, global_load_lds width=16, 2 barriers per K-step.
// ---------------------------------------------------------------------------
template <int ADD_BIAS, int OUT_BF16>
__global__ __launch_bounds__(256, 2) void gemm_bt(const bf16* __restrict__ A,
                                                  const bf16* __restrict__ Bt,
                                                  const float* __restrict__ bias,
                                                  void* __restrict__ C,
                                                  int M, int N, int K) {
    constexpr int BM = 128, BN = 128, BK = 32;
    __shared__ bf16 sA[BM * BK];
    __shared__ bf16 sB[BN * BK];

    const int tid = threadIdx.x;
    const int wave = tid >> 6;
    const int lane = tid & 63;
    const int wr = wave >> 1;   // 0..1 (M dir)
    const int wc = wave & 1;    // 0..1 (N dir)

    const int mBase = blockIdx.y * BM;
    const int nBase = blockIdx.x * BN;

    // staging: chunk index e = issue*256 + tid; row = e>>2, 16B-chunk = e&3
    const int r0 = tid >> 2, c0 = tid & 3;
    const int r1 = (256 + tid) >> 2, c1 = tid & 3;  // (256+tid)&3 == tid&3

    const bf16* gA0 = A + (size_t)(mBase + r0) * K + c0 * 8;
    const bf16* gA1 = A + (size_t)(mBase + r1) * K + c1 * 8;
    const bf16* gB0 = Bt + (size_t)(nBase + r0) * K + c0 * 8;
    const bf16* gB1 = Bt + (size_t)(nBase + r1) * K + c1 * 8;

    char* lA0 = (char*)sA + (wave * 64) * 16;
    char* lA1 = (char*)sA + (256 + wave * 64) * 16;
    char* lB0 = (char*)sB + (wave * 64) * 16;
    char* lB1 = (char*)sB + (256 + wave * 64) * 16;

    f32x4 acc[4][4];
    #pragma unroll
    for (int i = 0; i < 4; ++i)
        #pragma unroll
        for (int j = 0; j < 4; ++j) acc[i][j] = (f32x4){0.f, 0.f, 0.f, 0.f};

    const int aRow = wr * 64 + (lane & 15);
    const int bRow = wc * 64 + (lane & 15);
    const int kOff = (lane >> 4) * 8;

    for (int k0 = 0; k0 < K; k0 += BK) {
        LOAD_LDS16(gA0, lA0);
        LOAD_LDS16(gA1, lA1);
        LOAD_LDS16(gB0, lB0);
        LOAD_LDS16(gB1, lB1);
        gA0 += BK; gA1 += BK; gB0 += BK; gB1 += BK;
        __syncthreads();   // drains vmcnt before barrier (m97 semantics)

        bf16x8 af[4], bfr[4];
        #pragma unroll
        for (int mf = 0; mf < 4; ++mf)
            af[mf] = *reinterpret_cast<const bf16x8*>(&sA[(aRow + mf * 16) * BK + kOff]);
        #pragma unroll
        for (int nf = 0; nf < 4; ++nf)
            bfr[nf] = *reinterpret_cast<const bf16x8*>(&sB[(bRow + nf * 16) * BK + kOff]);
        #pragma unroll
        for (int mf = 0; mf < 4; ++mf)
            #pragma unroll
            for (int nf = 0; nf < 4; ++nf)
                acc[mf][nf] = __builtin_amdgcn_mfma_f32_16x16x32_bf16(
                    af[mf], bfr[nf], acc[mf][nf], 0, 0, 0);
        __syncthreads();
    }

    // epilogue — C/D layout: col = lane&15, row = (lane>>4)*4 + reg (m89-verified)
    const int cRow0 = mBase + wr * 64 + (lane >> 4) * 4;
    const int cCol0 = nBase + wc * 64 + (lane & 15);
    #pragma unroll
    for (int mf = 0; mf < 4; ++mf) {
        #pragma unroll
        for (int nf = 0; nf < 4; ++nf) {
            const int col = cCol0 + nf * 16;
            float bv = 0.f;
            if constexpr (ADD_BIAS) bv = bias[col];
            #pragma unroll
            for (int r = 0; r < 4; ++r) {
                const int row = cRow0 + mf * 16 + r;
                const float vres = acc[mf][nf][r] + bv;
                if constexpr (OUT_BF16)
                    ((bf16*)C)[(size_t)row * N + col] = __float2bfloat16(vres);
                else
                    ((float*)C)[(size_t)row * N + col] = vres;
            }
        }
    }
}

// ---------------------------------------------------------------------------
// launch: out = x_bf16 @ ((W_out·B) @ W_in)^T_bf16 + b_out
// ---------------------------------------------------------------------------
extern "C" void kernel_launch(void* const* d_in, const int* in_sizes, int n_in,
                              void* d_out, int out_size, void* d_ws, size_t ws_size,
                              hipStream_t stream) {
    const float* x     = (const float*)d_in[0];
    const float* w_in  = (const float*)d_in[1];
    const float* w_out = (const float*)d_in[2];
    const float* b_out = (const float*)d_in[3];
    const float* a_pad = (const float*)d_in[4];
    const float* b_pad = (const float*)d_in[5];
    float* out = (float*)d_out;

    char* ws = (char*)d_ws;
    bf16* x_bf   = (bf16*)ws;                                   // 67,108,864 B
    bf16* woutb  = (bf16*)(ws + (size_t)67108864);              //  8,388,608 B
    bf16* wint   = (bf16*)(ws + (size_t)75497472);              //  8,388,608 B
    bf16* mcomb  = (bf16*)(ws + (size_t)83886080);              //  8,388,608 B
    // total ws use: 92,274,688 B

    // x -> bf16 (33.5M elems, 8/thread)
    cvt_fp32_bf16<<<dim3(BATCH * NFEAT / (256 * 8)), dim3(256), 0, stream>>>(x, x_bf);
    // W_out * B (transposed rotations, reverse order), fp32 -> bf16
    butterfly_wout<<<dim3(NFEAT), dim3(256), 0, stream>>>(w_out, a_pad, b_pad, woutb);
    // W_in^T -> bf16
    transpose_cvt<<<dim3(NFEAT / 32, BDIM / 32), dim3(256), 0, stream>>>(w_in, wint);
    // M = (W_out·B) @ W_in  : A = woutb (o x k), Bt = wint (i x k) -> M[o,i] bf16
    gemm_bt<0, 1><<<dim3(NFEAT / 128, BDIM / 128), dim3(256), 0, stream>>>(
        woutb, wint, nullptr, mcomb, BDIM, NFEAT, BDIM);
    // out = x @ M^T + b : A = x_bf (r x i), Bt = mcomb (o x i) -> out fp32
    gemm_bt<1, 0><<<dim3(NFEAT / 128, BATCH / 128), dim3(256), 0, stream>>>(
        x_bf, mcomb, b_out, out, BATCH, NFEAT, NFEAT);
}

// Round 2
// 227.372 us; speedup vs baseline: 1.1531x; 1.1531x over previous
//
#include <hip/hip_runtime.h>
#include <hip/hip_bf16.h>

using bf16 = __hip_bfloat16;
using bf16x8 = __attribute__((ext_vector_type(8))) __bf16;
using f32x4 = __attribute__((ext_vector_type(4))) float;

typedef const __attribute__((address_space(1))) void* gas_ptr;
typedef __attribute__((address_space(3))) void* las_ptr;
#define LOAD_LDS16(g, l) \
    __builtin_amdgcn_global_load_lds((gas_ptr)(const void*)(g), (las_ptr)(void*)(l), 16, 0, 0)

#define LOG_DIM 11
#define BDIM 2048
#define NFEAT 2048
#define BATCH 16384

// ---------------------------------------------------------------------------
// 1) fp32 -> bf16 convert, 8 elems/thread
// ---------------------------------------------------------------------------
__global__ __launch_bounds__(256) void cvt_fp32_bf16(const float* __restrict__ in,
                                                     bf16* __restrict__ out) {
    size_t i = ((size_t)blockIdx.x * 256 + threadIdx.x) * 8;
    float4 v0 = *(const float4*)(in + i);
    float4 v1 = *(const float4*)(in + i + 4);
    union { bf16 h[8]; int4 v; } u;
    u.h[0] = __float2bfloat16(v0.x); u.h[1] = __float2bfloat16(v0.y);
    u.h[2] = __float2bfloat16(v0.z); u.h[3] = __float2bfloat16(v0.w);
    u.h[4] = __float2bfloat16(v1.x); u.h[5] = __float2bfloat16(v1.y);
    u.h[6] = __float2bfloat16(v1.z); u.h[7] = __float2bfloat16(v1.w);
    *(int4*)(out + i) = u.v;
}

// ---------------------------------------------------------------------------
// 2) WoutB[o,:] = W_out[o,:] * B  (transposed rotations, reverse level order)
// ---------------------------------------------------------------------------
__global__ __launch_bounds__(256) void butterfly_wout(const float* __restrict__ W,
                                                      const float* __restrict__ a_pad,
                                                      const float* __restrict__ b_pad,
                                                      bf16* __restrict__ out) {
    __shared__ float v[BDIM];
    const int o = blockIdx.x;
    const int t = threadIdx.x;
    const float* row = W + (size_t)o * BDIM;
    for (int i = t; i < BDIM / 4; i += 256)
        ((float4*)v)[i] = ((const float4*)row)[i];
    __syncthreads();
    for (int l = LOG_DIM - 1; l >= 0; --l) {
        const int bs = 1 << l;
        #pragma unroll
        for (int pp = 0; pp < 4; ++pp) {
            int p = t + pp * 256;
            int j = p >> l;
            int s = p & (bs - 1);
            int i0 = (j << (l + 1)) | s;
            int i1 = i0 + bs;
            float a = a_pad[l * (BDIM / 2) + j];
            float b = b_pad[l * (BDIM / 2) + j];
            float x0 = v[i0], x1 = v[i1];
            v[i0] = a * x0 - b * x1;
            v[i1] = b * x0 + a * x1;
        }
        __syncthreads();
    }
    union { bf16 h[8]; int4 vv; } u;
    #pragma unroll
    for (int j = 0; j < 8; ++j) u.h[j] = __float2bfloat16(v[t * 8 + j]);
    *(int4*)(out + (size_t)o * BDIM + t * 8) = u.vv;
}

// ---------------------------------------------------------------------------
// 3) WinT[i,k] = W_in[k,i], fp32 -> bf16
// ---------------------------------------------------------------------------
__global__ __launch_bounds__(256) void transpose_cvt(const float* __restrict__ in,
                                                     bf16* __restrict__ out) {
    __shared__ float tile[32][33];
    const int bx = blockIdx.x, by = blockIdx.y;
    const int tx = threadIdx.x & 31, ty = threadIdx.x >> 5;
    #pragma unroll
    for (int r = ty; r < 32; r += 8)
        tile[r][tx] = in[(size_t)(by * 32 + r) * NFEAT + bx * 32 + tx];
    __syncthreads();
    #pragma unroll
    for (int r = ty; r < 32; r += 8)
        out[(size_t)(bx * 32 + r) * NFEAT + by * 32 + tx] = __float2bfloat16(tile[tx][r]);
}

// ---------------------------------------------------------------------------
// 4) split-K 128x128 bf16 GEMM (m97 structure) for M = WoutB @ W_in
//    grid (N/128, M/128, 2): blockIdx.z picks K-half; bf16 partial outputs.
// ---------------------------------------------------------------------------
__global__ __launch_bounds__(256, 2) void gemm_bt_splitk(const bf16* __restrict__ A,
                                                         const bf16* __restrict__ Bt,
                                                         bf16* __restrict__ Cpart) {
    constexpr int BM = 128, BN = 128, BK = 32;
    constexpr int LDA = 2048, KLEN = 1024, NN = 2048;
    __shared__ bf16 sA[BM * BK];
    __shared__ bf16 sB[BN * BK];

    const int kz = blockIdx.z;
    A += kz * KLEN;
    Bt += kz * KLEN;
    bf16* C = Cpart + (size_t)kz * NN * NN;

    const int tid = threadIdx.x;
    const int wave = tid >> 6;
    const int lane = tid & 63;
    const int wr = wave >> 1;
    const int wc = wave & 1;

    const int mBase = blockIdx.y * BM;
    const int nBase = blockIdx.x * BN;

    const int r0 = tid >> 2, c0 = tid & 3;
    const int r1 = (256 + tid) >> 2;

    const bf16* gA0 = A + (size_t)(mBase + r0) * LDA + c0 * 8;
    const bf16* gA1 = A + (size_t)(mBase + r1) * LDA + c0 * 8;
    const bf16* gB0 = Bt + (size_t)(nBase + r0) * LDA + c0 * 8;
    const bf16* gB1 = Bt + (size_t)(nBase + r1) * LDA + c0 * 8;

    char* lA0 = (char*)sA + (wave * 64) * 16;
    char* lA1 = (char*)sA + (256 + wave * 64) * 16;
    char* lB0 = (char*)sB + (wave * 64) * 16;
    char* lB1 = (char*)sB + (256 + wave * 64) * 16;

    f32x4 acc[4][4];
    #pragma unroll
    for (int i = 0; i < 4; ++i)
        #pragma unroll
        for (int j = 0; j < 4; ++j) acc[i][j] = (f32x4){0.f, 0.f, 0.f, 0.f};

    const int aRow = wr * 64 + (lane & 15);
    const int bRow = wc * 64 + (lane & 15);
    const int kOff = (lane >> 4) * 8;

    for (int k0 = 0; k0 < KLEN; k0 += BK) {
        LOAD_LDS16(gA0, lA0);
        LOAD_LDS16(gA1, lA1);
        LOAD_LDS16(gB0, lB0);
        LOAD_LDS16(gB1, lB1);
        gA0 += BK; gA1 += BK; gB0 += BK; gB1 += BK;
        __syncthreads();

        bf16x8 af[4], bfr[4];
        #pragma unroll
        for (int mf = 0; mf < 4; ++mf)
            af[mf] = *reinterpret_cast<const bf16x8*>(&sA[(aRow + mf * 16) * BK + kOff]);
        #pragma unroll
        for (int nf = 0; nf < 4; ++nf)
            bfr[nf] = *reinterpret_cast<const bf16x8*>(&sB[(bRow + nf * 16) * BK + kOff]);
        #pragma unroll
        for (int mf = 0; mf < 4; ++mf)
            #pragma unroll
            for (int nf = 0; nf < 4; ++nf)
                acc[mf][nf] = __builtin_amdgcn_mfma_f32_16x16x32_bf16(
                    af[mf], bfr[nf], acc[mf][nf], 0, 0, 0);
        __syncthreads();
    }

    const int cRow0 = mBase + wr * 64 + (lane >> 4) * 4;
    const int cCol0 = nBase + wc * 64 + (lane & 15);
    #pragma unroll
    for (int mf = 0; mf < 4; ++mf)
        #pragma unroll
        for (int nf = 0; nf < 4; ++nf)
            #pragma unroll
            for (int r = 0; r < 4; ++r)
                C[(size_t)(cRow0 + mf * 16 + r) * NN + cCol0 + nf * 16] =
                    __float2bfloat16(acc[mf][nf][r]);
}

// ---------------------------------------------------------------------------
// 5) add two bf16 partials -> bf16
// ---------------------------------------------------------------------------
__global__ __launch_bounds__(256) void addcvt(const bf16* __restrict__ p0,
                                              const bf16* __restrict__ p1,
                                              bf16* __restrict__ out) {
    size_t i = ((size_t)blockIdx.x * 256 + threadIdx.x) * 8;
    union { bf16 h[8]; int4 v; } a, b, o;
    a.v = *(const int4*)(p0 + i);
    b.v = *(const int4*)(p1 + i);
    #pragma unroll
    for (int j = 0; j < 8; ++j)
        o.h[j] = __float2bfloat16(__bfloat162float(a.h[j]) + __bfloat162float(b.h[j]));
    *(int4*)(out + i) = o.v;
}

// ---------------------------------------------------------------------------
// 6) Main GEMM: 256x256 tile, BK=64, 8-phase schedule (T1+T2+T3+T4+T5).
//    C[m,n] = sum_k A[m,k]*Bt[n,k] + bias[n].  M=16384 N=2048 K=2048 fixed.
//    8 waves (2M x 4N), per-wave 128x64 C. LDS 128KB: 2 slots x {A,B} x 2 kh.
//    Region = [256 rows][32 k] bf16 (16KB), staged by 2 x global_load_lds(16B).
//    Swizzle: phys kc-chunk = kc ^ ((row>>2)&3); applied on stage SOURCE
//    (gload_lds dest is linear) and folded into read offsets (kcx).
// ---------------------------------------------------------------------------
#define GK 2048
#define LDS_SLOT 65536
#define LDS_BOFF 32768
#define LDS_KH 16384

__global__ __launch_bounds__(512, 2) void gemm256(const bf16* __restrict__ A,
                                                  const bf16* __restrict__ Bt,
                                                  const float* __restrict__ bias,
                                                  float* __restrict__ C) {
    __shared__ __align__(16) char lds[131072];

    const int tid = threadIdx.x;
    const int wave = tid >> 6, lane = tid & 63;
    const int l15 = lane & 15, kc = lane >> 4;
    const int wm = wave >> 2, wn = wave & 3;

    // T1: bijective XCD swizzle (512 wgs, 512%8==0)
    const int bid = blockIdx.x;
    const int swz = (bid & 7) * 64 + (bid >> 3);
    const int bm = swz >> 3, bn = swz & 7;
    const int mBase = bm * 256, nBase = bn * 256;

    // stage source (pre-swizzled): chunk c = e*512+tid; logical = c ^ ((c>>4)&3)
    const int c_log = tid ^ ((tid >> 4) & 3);
    const int srow = c_log >> 2, skc = c_log & 3;
    const bf16* gA = A + (size_t)(mBase + srow) * GK + skc * 8;
    const bf16* gB = Bt + (size_t)(nBase + srow) * GK + skc * 8;
    const int stgBase = wave * 1024;   // lane*16 implicit in gload_lds

    // read offsets: swizzle folds to per-thread constant (row bits 2:3 == l15>>2)
    const int kcx = kc ^ ((l15 >> 2) & 3);
    const int aoff = wm * 8192 + l15 * 64 + kcx * 16;
    const int boff = LDS_BOFF + wn * 4096 + l15 * 64 + kcx * 16;

    f32x4 acc[8][4];
    #pragma unroll
    for (int i = 0; i < 8; ++i)
        #pragma unroll
        for (int j = 0; j < 4; ++j) acc[i][j] = (f32x4){0.f, 0.f, 0.f, 0.f};
    bf16x8 bfr[4];

#define STG(GSRC, LDSC, KT, KH) do {                                        \
    const bf16* _g = (GSRC) + (KT) * 64 + (KH) * 32;                        \
    LOAD_LDS16(_g, lds + (LDSC) + stgBase);                                 \
    LOAD_LDS16(_g + (size_t)128 * GK, lds + (LDSC) + stgBase + 8192);       \
} while (0)

    // prologue: slot0 complete (tile 0) first, then 3 regions of slot1 (tile 1)
    STG(gA, 0 * LDS_SLOT + 0, 0, 0);
    STG(gB, 0 * LDS_SLOT + LDS_BOFF + 0, 0, 0);
    STG(gA, 0 * LDS_SLOT + LDS_KH, 0, 1);
    STG(gB, 0 * LDS_SLOT + LDS_BOFF + LDS_KH, 0, 1);
    STG(gA, 1 * LDS_SLOT + 0, 1, 0);
    STG(gB, 1 * LDS_SLOT + LDS_BOFF + 0, 1, 0);
    STG(gB, 1 * LDS_SLOT + LDS_BOFF + LDS_KH, 1, 1);
    asm volatile("s_waitcnt vmcnt(6)");   // 14 issued -> first 8 (slot0) landed
    __builtin_amdgcn_s_barrier();

    // phase: compute (SLOT,KH,MH) quadrant; stage one freed region; vmcnt at P4/P8
#define PHASE(SLOT, KH, MH, SGSRC, SLDS, SKT, SKH, DOVM) do {               \
    const int _rb = (SLOT) * LDS_SLOT + (KH) * LDS_KH;                      \
    bf16x8 _a[4];                                                           \
    _Pragma("unroll")                                                       \
    for (int _mf = 0; _mf < 4; ++_mf)                                       \
        _a[_mf] = *(const bf16x8*)(lds + _rb + aoff + (MH) * 4096 + _mf * 1024); \
    if (!(MH)) {                                                            \
        _Pragma("unroll")                                                   \
        for (int _nf = 0; _nf < 4; ++_nf)                                   \
            bfr[_nf] = *(const bf16x8*)(lds + _rb + boff + _nf * 1024);     \
    }                                                                       \
    STG(SGSRC, SLDS, SKT, SKH);                                             \
    if (DOVM) asm volatile("s_waitcnt vmcnt(6)");                           \
    __builtin_amdgcn_s_barrier();                                           \
    asm volatile("s_waitcnt lgkmcnt(0)");                                   \
    __builtin_amdgcn_s_setprio(1);                                          \
    _Pragma("unroll")                                                       \
    for (int _mf = 0; _mf < 4; ++_mf)                                       \
        _Pragma("unroll")                                                   \
        for (int _nf = 0; _nf < 4; ++_nf)                                   \
            acc[(MH) * 4 + _mf][_nf] = __builtin_amdgcn_mfma_f32_16x16x32_bf16( \
                _a[_mf], bfr[_nf], acc[(MH) * 4 + _mf][_nf], 0, 0, 0);      \
    __builtin_amdgcn_s_setprio(0);                                          \
    __builtin_amdgcn_s_barrier();                                           \
} while (0)

    // 32 K-tiles, 2 per iteration. Stage targets freed exactly 1 phase earlier;
    // wrap (&31) on the tail re-stages valid memory into dead regions.
    for (int it = 0; it < 16; ++it) {
        const int t0 = 2 * it;
        const int t1 = (t0 + 1) & 31, t2 = (t0 + 2) & 31, t3 = (t0 + 3) & 31;
        PHASE(0, 0, 0, gA, 1 * LDS_SLOT + LDS_KH,            t1, 1, 0);
        PHASE(0, 0, 1, gB, 0 * LDS_SLOT + LDS_BOFF,          t2, 0, 0);
        PHASE(0, 1, 0, gA, 0 * LDS_SLOT + 0,                 t2, 0, 0);
        PHASE(0, 1, 1, gB, 0 * LDS_SLOT + LDS_BOFF + LDS_KH, t2, 1, 1);
        PHASE(1, 0, 0, gA, 0 * LDS_SLOT + LDS_KH,            t2, 1, 0);
        PHASE(1, 0, 1, gB, 1 * LDS_SLOT + LDS_BOFF,          t3, 0, 0);
        PHASE(1, 1, 0, gA, 1 * LDS_SLOT + 0,                 t3, 0, 0);
        PHASE(1, 1, 1, gB, 1 * LDS_SLOT + LDS_BOFF + LDS_KH, t3, 1, 1);
    }

    // epilogue: C/D layout col=lane&15, row=(lane>>4)*4+reg (m89-verified)
    const int cRow0 = mBase + wm * 128 + (lane >> 4) * 4;
    const int cCol0 = nBase + wn * 64 + l15;
    float bv[4];
    #pragma unroll
    for (int nf = 0; nf < 4; ++nf) bv[nf] = bias[cCol0 + nf * 16];
    #pragma unroll
    for (int Mf = 0; Mf < 8; ++Mf)
        #pragma unroll
        for (int nf = 0; nf < 4; ++nf)
            #pragma unroll
            for (int r = 0; r < 4; ++r)
                C[(size_t)(cRow0 + Mf * 16 + r) * GK + cCol0 + nf * 16] =
                    acc[Mf][nf][r] + bv[nf];
#undef PHASE
#undef STG
}

// ---------------------------------------------------------------------------
// launch
// ---------------------------------------------------------------------------
extern "C" void kernel_launch(void* const* d_in, const int* in_sizes, int n_in,
                              void* d_out, int out_size, void* d_ws, size_t ws_size,
                              hipStream_t stream) {
    const float* x     = (const float*)d_in[0];
    const float* w_in  = (const float*)d_in[1];
    const float* w_out = (const float*)d_in[2];
    const float* b_out = (const float*)d_in[3];
    const float* a_pad = (const float*)d_in[4];
    const float* b_pad = (const float*)d_in[5];
    float* out = (float*)d_out;

    char* ws = (char*)d_ws;
    bf16* x_bf  = (bf16*)ws;                        // 67,108,864 B
    bf16* woutb = (bf16*)(ws + (size_t)67108864);   //  8,388,608 B
    bf16* wint  = (bf16*)(ws + (size_t)75497472);   //  8,388,608 B
    bf16* mcomb = (bf16*)(ws + (size_t)83886080);   //  8,388,608 B  (ws total 92 MB)

    // split-K partials live in d_out (134 MB, fully overwritten by gemm256)
    bf16* part = (bf16*)d_out;                      // 2 x 8 MB

    cvt_fp32_bf16<<<dim3(BATCH * NFEAT / (256 * 8)), dim3(256), 0, stream>>>(x, x_bf);
    butterfly_wout<<<dim3(NFEAT), dim3(256), 0, stream>>>(w_out, a_pad, b_pad, woutb);
    transpose_cvt<<<dim3(NFEAT / 32, BDIM / 32), dim3(256), 0, stream>>>(w_in, wint);
    // M = (W_out·B) @ W_in, split-K=2 (512 wgs in one launch)
    gemm_bt_splitk<<<dim3(NFEAT / 128, BDIM / 128, 2), dim3(256), 0, stream>>>(
        woutb, wint, part);
    addcvt<<<dim3(NFEAT * BDIM / (256 * 8)), dim3(256), 0, stream>>>(
        part, part + (size_t)NFEAT * BDIM, mcomb);
    // out = x @ M^T + b  (8-phase 256^2)
    gemm256<<<dim3((BATCH / 256) * (NFEAT / 256)), dim3(512), 0, stream>>>(
        x_bf, mcomb, b_out, out);
}

// Round 3
// 223.738 us; speedup vs baseline: 1.1718x; 1.0162x over previous
//
#include <hip/hip_runtime.h>
#include <hip/hip_bf16.h>

using bf16 = __hip_bfloat16;
using bf16x8 = __attribute__((ext_vector_type(8))) __bf16;
using f32x4 = __attribute__((ext_vector_type(4))) float;

typedef const __attribute__((address_space(1))) void* gas_ptr;
typedef __attribute__((address_space(3))) void* las_ptr;
#define LOAD_LDS16(g, l) \
    __builtin_amdgcn_global_load_lds((gas_ptr)(const void*)(g), (las_ptr)(void*)(l), 16, 0, 0)

#define LOG_DIM 11
#define BDIM 2048
#define NFEAT 2048
#define BATCH 16384

// ---------------------------------------------------------------------------
// 1) fp32 -> bf16 convert, 8 elems/thread
// ---------------------------------------------------------------------------
__global__ __launch_bounds__(256) void cvt_fp32_bf16(const float* __restrict__ in,
                                                     bf16* __restrict__ out) {
    size_t i = ((size_t)blockIdx.x * 256 + threadIdx.x) * 8;
    float4 v0 = *(const float4*)(in + i);
    float4 v1 = *(const float4*)(in + i + 4);
    union { bf16 h[8]; int4 v; } u;
    u.h[0] = __float2bfloat16(v0.x); u.h[1] = __float2bfloat16(v0.y);
    u.h[2] = __float2bfloat16(v0.z); u.h[3] = __float2bfloat16(v0.w);
    u.h[4] = __float2bfloat16(v1.x); u.h[5] = __float2bfloat16(v1.y);
    u.h[6] = __float2bfloat16(v1.z); u.h[7] = __float2bfloat16(v1.w);
    *(int4*)(out + i) = u.v;
}

// ---------------------------------------------------------------------------
// 2) WoutB[o,:] = W_out[o,:] * B  (transposed rotations, reverse level order)
// ---------------------------------------------------------------------------
__global__ __launch_bounds__(256) void butterfly_wout(const float* __restrict__ W,
                                                      const float* __restrict__ a_pad,
                                                      const float* __restrict__ b_pad,
                                                      bf16* __restrict__ out) {
    __shared__ float v[BDIM];
    const int o = blockIdx.x;
    const int t = threadIdx.x;
    const float* row = W + (size_t)o * BDIM;
    for (int i = t; i < BDIM / 4; i += 256)
        ((float4*)v)[i] = ((const float4*)row)[i];
    __syncthreads();
    for (int l = LOG_DIM - 1; l >= 0; --l) {
        const int bs = 1 << l;
        #pragma unroll
        for (int pp = 0; pp < 4; ++pp) {
            int p = t + pp * 256;
            int j = p >> l;
            int s = p & (bs - 1);
            int i0 = (j << (l + 1)) | s;
            int i1 = i0 + bs;
            float a = a_pad[l * (BDIM / 2) + j];
            float b = b_pad[l * (BDIM / 2) + j];
            float x0 = v[i0], x1 = v[i1];
            v[i0] = a * x0 - b * x1;
            v[i1] = b * x0 + a * x1;
        }
        __syncthreads();
    }
    union { bf16 h[8]; int4 vv; } u;
    #pragma unroll
    for (int j = 0; j < 8; ++j) u.h[j] = __float2bfloat16(v[t * 8 + j]);
    *(int4*)(out + (size_t)o * BDIM + t * 8) = u.vv;
}

// ---------------------------------------------------------------------------
// 3) WinT[i,k] = W_in[k,i], fp32 -> bf16
// ---------------------------------------------------------------------------
__global__ __launch_bounds__(256) void transpose_cvt(const float* __restrict__ in,
                                                     bf16* __restrict__ out) {
    __shared__ float tile[32][33];
    const int bx = blockIdx.x, by = blockIdx.y;
    const int tx = threadIdx.x & 31, ty = threadIdx.x >> 5;
    #pragma unroll
    for (int r = ty; r < 32; r += 8)
        tile[r][tx] = in[(size_t)(by * 32 + r) * NFEAT + bx * 32 + tx];
    __syncthreads();
    #pragma unroll
    for (int r = ty; r < 32; r += 8)
        out[(size_t)(bx * 32 + r) * NFEAT + by * 32 + tx] = __float2bfloat16(tile[tx][r]);
}

// ---------------------------------------------------------------------------
// 4) split-K=4 128x128 bf16 GEMM (m97 structure) for M = WoutB @ W_in
//    grid (16, 16, 4): blockIdx.z picks K quarter (K=512); bf16 partials.
// ---------------------------------------------------------------------------
__global__ __launch_bounds__(256, 2) void gemm_bt_splitk(const bf16* __restrict__ A,
                                                         const bf16* __restrict__ Bt,
                                                         bf16* __restrict__ Cpart) {
    constexpr int BM = 128, BN = 128, BK = 32;
    constexpr int LDA = 2048, KLEN = 512, NN = 2048;
    __shared__ bf16 sA[BM * BK];
    __shared__ bf16 sB[BN * BK];

    const int kz = blockIdx.z;
    A += kz * KLEN;
    Bt += kz * KLEN;
    bf16* C = Cpart + (size_t)kz * NN * NN;

    const int tid = threadIdx.x;
    const int wave = tid >> 6;
    const int lane = tid & 63;
    const int wr = wave >> 1;
    const int wc = wave & 1;

    const int mBase = blockIdx.y * BM;
    const int nBase = blockIdx.x * BN;

    const int r0 = tid >> 2, c0 = tid & 3;
    const int r1 = (256 + tid) >> 2;

    const bf16* gA0 = A + (size_t)(mBase + r0) * LDA + c0 * 8;
    const bf16* gA1 = A + (size_t)(mBase + r1) * LDA + c0 * 8;
    const bf16* gB0 = Bt + (size_t)(nBase + r0) * LDA + c0 * 8;
    const bf16* gB1 = Bt + (size_t)(nBase + r1) * LDA + c0 * 8;

    char* lA0 = (char*)sA + (wave * 64) * 16;
    char* lA1 = (char*)sA + (256 + wave * 64) * 16;
    char* lB0 = (char*)sB + (wave * 64) * 16;
    char* lB1 = (char*)sB + (256 + wave * 64) * 16;

    f32x4 acc[4][4];
    #pragma unroll
    for (int i = 0; i < 4; ++i)
        #pragma unroll
        for (int j = 0; j < 4; ++j) acc[i][j] = (f32x4){0.f, 0.f, 0.f, 0.f};

    const int aRow = wr * 64 + (lane & 15);
    const int bRow = wc * 64 + (lane & 15);
    const int kOff = (lane >> 4) * 8;

    for (int k0 = 0; k0 < KLEN; k0 += BK) {
        LOAD_LDS16(gA0, lA0);
        LOAD_LDS16(gA1, lA1);
        LOAD_LDS16(gB0, lB0);
        LOAD_LDS16(gB1, lB1);
        gA0 += BK; gA1 += BK; gB0 += BK; gB1 += BK;
        __syncthreads();

        bf16x8 af[4], bfr[4];
        #pragma unroll
        for (int mf = 0; mf < 4; ++mf)
            af[mf] = *reinterpret_cast<const bf16x8*>(&sA[(aRow + mf * 16) * BK + kOff]);
        #pragma unroll
        for (int nf = 0; nf < 4; ++nf)
            bfr[nf] = *reinterpret_cast<const bf16x8*>(&sB[(bRow + nf * 16) * BK + kOff]);
        #pragma unroll
        for (int mf = 0; mf < 4; ++mf)
            #pragma unroll
            for (int nf = 0; nf < 4; ++nf)
                acc[mf][nf] = __builtin_amdgcn_mfma_f32_16x16x32_bf16(
                    af[mf], bfr[nf], acc[mf][nf], 0, 0, 0);
        __syncthreads();
    }

    const int cRow0 = mBase + wr * 64 + (lane >> 4) * 4;
    const int cCol0 = nBase + wc * 64 + (lane & 15);
    #pragma unroll
    for (int mf = 0; mf < 4; ++mf)
        #pragma unroll
        for (int nf = 0; nf < 4; ++nf)
            #pragma unroll
            for (int r = 0; r < 4; ++r)
                C[(size_t)(cRow0 + mf * 16 + r) * NN + cCol0 + nf * 16] =
                    __float2bfloat16(acc[mf][nf][r]);
}

// ---------------------------------------------------------------------------
// 5) add four bf16 partials -> bf16
// ---------------------------------------------------------------------------
__global__ __launch_bounds__(256) void addcvt4(const bf16* __restrict__ p,
                                               bf16* __restrict__ out) {
    size_t i = ((size_t)blockIdx.x * 256 + threadIdx.x) * 8;
    constexpr size_t STRIDE = (size_t)2048 * 2048;
    float s[8];
    #pragma unroll
    for (int j = 0; j < 8; ++j) s[j] = 0.f;
    #pragma unroll
    for (int z = 0; z < 4; ++z) {
        union { bf16 h[8]; int4 v; } a;
        a.v = *(const int4*)(p + z * STRIDE + i);
        #pragma unroll
        for (int j = 0; j < 8; ++j) s[j] += __bfloat162float(a.h[j]);
    }
    union { bf16 h[8]; int4 v; } o;
    #pragma unroll
    for (int j = 0; j < 8; ++j) o.h[j] = __float2bfloat16(s[j]);
    *(int4*)(out + i) = o.v;
}

// ---------------------------------------------------------------------------
// 6) Main GEMM: 256x256 tile, BK=64, 8-phase schedule (T1+T2+T3+T4+T5).
//    C[m,n] = sum_k A[m,k]*Bt[n,k] + bias[n].  M=16384 N=2048 K=2048 fixed.
//    8 waves (2M x 4N), per-wave 128x64 C. LDS 128KB: 2 slots x {A,B} x 2 kh.
//    Region = [256 rows][32 k] bf16 (16KB), staged by 2 x global_load_lds(16B).
//    Swizzle (FIXED r2->r3): phys kc-chunk = kc ^ ((row>>1)&3).  Row stride is
//    64B so only row-bit0 reaches addr%128; XOR by row bits 1:2 makes every
//    consecutive-8-lane group of ds_read_b128 cover {0,16,..,112}%128 -- all
//    32 banks exactly once (round-2's bits 2:3 left even-lane pairs aliased).
//    Applied on stage SOURCE (gload_lds dest linear, rule #21) and folded
//    into read offset kcx.
// ---------------------------------------------------------------------------
#define GK 2048
#define LDS_SLOT 65536
#define LDS_BOFF 32768
#define LDS_KH 16384

__global__ __launch_bounds__(512, 2) void gemm256(const bf16* __restrict__ A,
                                                  const bf16* __restrict__ Bt,
                                                  const float* __restrict__ bias,
                                                  float* __restrict__ C) {
    __shared__ __align__(16) char lds[131072];

    const int tid = threadIdx.x;
    const int wave = tid >> 6, lane = tid & 63;
    const int l15 = lane & 15, kc = lane >> 4;
    const int wm = wave >> 2, wn = wave & 3;

    // T1: bijective XCD swizzle (512 wgs, 512%8==0)
    const int bid = blockIdx.x;
    const int swz = (bid & 7) * 64 + (bid >> 3);
    const int bm = swz >> 3, bn = swz & 7;
    const int mBase = bm * 256, nBase = bn * 256;

    // stage source (pre-swizzled): phys chunk tid -> logical chunk tid^((tid>>3)&3)
    const int c_log = tid ^ ((tid >> 3) & 3);
    const int srow = c_log >> 2, skc = c_log & 3;
    const bf16* gA = A + (size_t)(mBase + srow) * GK + skc * 8;
    const bf16* gB = Bt + (size_t)(nBase + srow) * GK + skc * 8;
    const int stgBase = wave * 1024;

    // read offsets: kcx = kc ^ (row bits 1:2) = kc ^ ((l15>>1)&3)
    const int kcx = kc ^ ((l15 >> 1) & 3);
    const int aoff = wm * 8192 + l15 * 64 + kcx * 16;
    const int boff = LDS_BOFF + wn * 4096 + l15 * 64 + kcx * 16;

    f32x4 acc[8][4];
    #pragma unroll
    for (int i = 0; i < 8; ++i)
        #pragma unroll
        for (int j = 0; j < 4; ++j) acc[i][j] = (f32x4){0.f, 0.f, 0.f, 0.f};
    bf16x8 bfr[4];

#define STG(GSRC, LDSC, KT, KH) do {                                        \
    const bf16* _g = (GSRC) + (KT) * 64 + (KH) * 32;                        \
    LOAD_LDS16(_g, lds + (LDSC) + stgBase);                                 \
    LOAD_LDS16(_g + (size_t)128 * GK, lds + (LDSC) + stgBase + 8192);       \
} while (0)

    // prologue: slot0 complete (tile 0) first, then 3 regions of slot1 (tile 1)
    STG(gA, 0 * LDS_SLOT + 0, 0, 0);
    STG(gB, 0 * LDS_SLOT + LDS_BOFF + 0, 0, 0);
    STG(gA, 0 * LDS_SLOT + LDS_KH, 0, 1);
    STG(gB, 0 * LDS_SLOT + LDS_BOFF + LDS_KH, 0, 1);
    STG(gA, 1 * LDS_SLOT + 0, 1, 0);
    STG(gB, 1 * LDS_SLOT + LDS_BOFF + 0, 1, 0);
    STG(gB, 1 * LDS_SLOT + LDS_BOFF + LDS_KH, 1, 1);
    asm volatile("s_waitcnt vmcnt(6)");   // 14 issued -> first 8 (slot0) landed
    __builtin_amdgcn_s_barrier();

    // phase: compute (SLOT,KH,MH) quadrant; stage one freed region; vmcnt at P4/P8
#define PHASE(SLOT, KH, MH, SGSRC, SLDS, SKT, SKH, DOVM) do {               \
    const int _rb = (SLOT) * LDS_SLOT + (KH) * LDS_KH;                      \
    bf16x8 _a[4];                                                           \
    _Pragma("unroll")                                                       \
    for (int _mf = 0; _mf < 4; ++_mf)                                       \
        _a[_mf] = *(const bf16x8*)(lds + _rb + aoff + (MH) * 4096 + _mf * 1024); \
    if (!(MH)) {                                                            \
        _Pragma("unroll")                                                   \
        for (int _nf = 0; _nf < 4; ++_nf)                                   \
            bfr[_nf] = *(const bf16x8*)(lds + _rb + boff + _nf * 1024);     \
    }                                                                       \
    STG(SGSRC, SLDS, SKT, SKH);                                             \
    if (DOVM) asm volatile("s_waitcnt vmcnt(6)");                           \
    __builtin_amdgcn_s_barrier();                                           \
    asm volatile("s_waitcnt lgkmcnt(0)");                                   \
    __builtin_amdgcn_s_setprio(1);                                          \
    _Pragma("unroll")                                                       \
    for (int _mf = 0; _mf < 4; ++_mf)                                       \
        _Pragma("unroll")                                                   \
        for (int _nf = 0; _nf < 4; ++_nf)                                   \
            acc[(MH) * 4 + _mf][_nf] = __builtin_amdgcn_mfma_f32_16x16x32_bf16( \
                _a[_mf], bfr[_nf], acc[(MH) * 4 + _mf][_nf], 0, 0, 0);      \
    __builtin_amdgcn_s_setprio(0);                                          \
    __builtin_amdgcn_s_barrier();                                           \
} while (0)

    // 32 K-tiles, 2 per iteration. Stage targets freed exactly 1 phase earlier;
    // wrap (&31) on the tail re-stages valid memory into dead regions.
    for (int it = 0; it < 16; ++it) {
        const int t0 = 2 * it;
        const int t1 = (t0 + 1) & 31, t2 = (t0 + 2) & 31, t3 = (t0 + 3) & 31;
        PHASE(0, 0, 0, gA, 1 * LDS_SLOT + LDS_KH,            t1, 1, 0);
        PHASE(0, 0, 1, gB, 0 * LDS_SLOT + LDS_BOFF,          t2, 0, 0);
        PHASE(0, 1, 0, gA, 0 * LDS_SLOT + 0,                 t2, 0, 0);
        PHASE(0, 1, 1, gB, 0 * LDS_SLOT + LDS_BOFF + LDS_KH, t2, 1, 1);
        PHASE(1, 0, 0, gA, 0 * LDS_SLOT + LDS_KH,            t2, 1, 0);
        PHASE(1, 0, 1, gB, 1 * LDS_SLOT + LDS_BOFF,          t3, 0, 0);
        PHASE(1, 1, 0, gA, 1 * LDS_SLOT + 0,                 t3, 0, 0);
        PHASE(1, 1, 1, gB, 1 * LDS_SLOT + LDS_BOFF + LDS_KH, t3, 1, 1);
    }

    // epilogue: C/D layout col=lane&15, row=(lane>>4)*4+reg (m89-verified)
    const int cRow0 = mBase + wm * 128 + (lane >> 4) * 4;
    const int cCol0 = nBase + wn * 64 + l15;
    float bv[4];
    #pragma unroll
    for (int nf = 0; nf < 4; ++nf) bv[nf] = bias[cCol0 + nf * 16];
    #pragma unroll
    for (int Mf = 0; Mf < 8; ++Mf)
        #pragma unroll
        for (int nf = 0; nf < 4; ++nf)
            #pragma unroll
            for (int r = 0; r < 4; ++r)
                C[(size_t)(cRow0 + Mf * 16 + r) * GK + cCol0 + nf * 16] =
                    acc[Mf][nf][r] + bv[nf];
#undef PHASE
#undef STG
}

// ---------------------------------------------------------------------------
// launch
// ---------------------------------------------------------------------------
extern "C" void kernel_launch(void* const* d_in, const int* in_sizes, int n_in,
                              void* d_out, int out_size, void* d_ws, size_t ws_size,
                              hipStream_t stream) {
    const float* x     = (const float*)d_in[0];
    const float* w_in  = (const float*)d_in[1];
    const float* w_out = (const float*)d_in[2];
    const float* b_out = (const float*)d_in[3];
    const float* a_pad = (const float*)d_in[4];
    const float* b_pad = (const float*)d_in[5];
    float* out = (float*)d_out;

    char* ws = (char*)d_ws;
    bf16* x_bf  = (bf16*)ws;                        // 67,108,864 B
    bf16* woutb = (bf16*)(ws + (size_t)67108864);   //  8,388,608 B
    bf16* wint  = (bf16*)(ws + (size_t)75497472);   //  8,388,608 B
    bf16* mcomb = (bf16*)(ws + (size_t)83886080);   //  8,388,608 B  (ws total 92 MB)

    // split-K partials live in d_out (134 MB, fully overwritten by gemm256)
    bf16* part = (bf16*)d_out;                      // 4 x 8 MB

    cvt_fp32_bf16<<<dim3(BATCH * NFEAT / (256 * 8)), dim3(256), 0, stream>>>(x, x_bf);
    butterfly_wout<<<dim3(NFEAT), dim3(256), 0, stream>>>(w_out, a_pad, b_pad, woutb);
    transpose_cvt<<<dim3(NFEAT / 32, BDIM / 32), dim3(256), 0, stream>>>(w_in, wint);
    // M = (W_out·B) @ W_in, split-K=4 (1024 wgs in one launch)
    gemm_bt_splitk<<<dim3(NFEAT / 128, BDIM / 128, 4), dim3(256), 0, stream>>>(
        woutb, wint, part);
    addcvt4<<<dim3(NFEAT * BDIM / (256 * 8)), dim3(256), 0, stream>>>(part, mcomb);
    // out = x @ M^T + b  (8-phase 256^2)
    gemm256<<<dim3((BATCH / 256) * (NFEAT / 256)), dim3(512), 0, stream>>>(
        x_bf, mcomb, b_out, out);
}

// Round 4
// 205.721 us; speedup vs baseline: 1.2744x; 1.0876x over previous
//
#include <hip/hip_runtime.h>
#include <hip/hip_bf16.h>

using bf16 = __hip_bfloat16;
using bf16x8 = __attribute__((ext_vector_type(8))) __bf16;
using f32x4 = __attribute__((ext_vector_type(4))) float;

typedef const __attribute__((address_space(1))) void* gas_ptr;
typedef __attribute__((address_space(3))) void* las_ptr;
#define LOAD_LDS16(g, l) \
    __builtin_amdgcn_global_load_lds((gas_ptr)(const void*)(g), (las_ptr)(void*)(l), 16, 0, 0)

#define LOG_DIM 11
#define BDIM 2048
#define NFEAT 2048
#define BATCH 16384

// ---------------------------------------------------------------------------
// prep1: butterfly_wout (blocks 0..2047)  ||  transpose_cvt (blocks 2048..6143)
//   WoutB[o,:] = W_out[o,:]*B (transposed rotations, reverse order) -> bf16
//   WinT[i,k]  = W_in[k,i] -> bf16
// Per-block uniform branch; both __shared__ arrays coexist (12.4 KB).
// ---------------------------------------------------------------------------
__global__ __launch_bounds__(256) void prep1(const float* __restrict__ w_out,
                                             const float* __restrict__ a_pad,
                                             const float* __restrict__ b_pad,
                                             const float* __restrict__ w_in,
                                             bf16* __restrict__ woutb,
                                             bf16* __restrict__ wint) {
    __shared__ float v[BDIM];
    __shared__ float tile[32][33];
    const int t = threadIdx.x;
    if (blockIdx.x < 2048) {
        const int o = blockIdx.x;
        const float* row = w_out + (size_t)o * BDIM;
        for (int i = t; i < BDIM / 4; i += 256)
            ((float4*)v)[i] = ((const float4*)row)[i];
        __syncthreads();
        for (int l = LOG_DIM - 1; l >= 0; --l) {
            #pragma unroll
            for (int pp = 0; pp < 4; ++pp) {
                int p = t + pp * 256;
                int j = p >> l;
                int s = p & ((1 << l) - 1);
                int i0 = (j << (l + 1)) | s;
                int i1 = i0 + (1 << l);
                float a = a_pad[l * (BDIM / 2) + j];
                float b = b_pad[l * (BDIM / 2) + j];
                float x0 = v[i0], x1 = v[i1];
                v[i0] = a * x0 - b * x1;
                v[i1] = b * x0 + a * x1;
            }
            __syncthreads();
        }
        union { bf16 h[8]; int4 vv; } u;
        #pragma unroll
        for (int j = 0; j < 8; ++j) u.h[j] = __float2bfloat16(v[t * 8 + j]);
        *(int4*)(woutb + (size_t)o * BDIM + t * 8) = u.vv;
    } else {
        const int b = blockIdx.x - 2048;
        const int bx = b & 63, by = b >> 6;
        const int tx = t & 31, ty = t >> 5;
        #pragma unroll
        for (int r = ty; r < 32; r += 8)
            tile[r][tx] = w_in[(size_t)(by * 32 + r) * NFEAT + bx * 32 + tx];
        __syncthreads();
        #pragma unroll
        for (int r = ty; r < 32; r += 8)
            wint[(size_t)(bx * 32 + r) * NFEAT + by * 32 + tx] = __float2bfloat16(tile[tx][r]);
    }
}

// ---------------------------------------------------------------------------
// prep2: splitk M-GEMM (even blocks)  ||  x fp32->bf16 convert (odd blocks)
//   splitk: M = WoutB @ W_in^T-layout, 128x128 tile, K=512 per kz, bf16 partials
//   cvt: 1024 virtual blocks x 16 iters x 2048 elems, vectorized 8/thread
// Grid 2048, parity interleave -> BW-bound cvt overlaps compute-bound GEMM.
// ---------------------------------------------------------------------------
__global__ __launch_bounds__(256, 2) void prep2(const bf16* __restrict__ Aw,
                                                const bf16* __restrict__ Btw,
                                                bf16* __restrict__ Cpart,
                                                const float* __restrict__ x,
                                                bf16* __restrict__ x_bf) {
    __shared__ bf16 sA[128 * 32];
    __shared__ bf16 sB[128 * 32];
    const int tid = threadIdx.x;

    if (blockIdx.x & 1) {
        // ---- cvt part ----
        const int vb = blockIdx.x >> 1;   // 0..1023
        #pragma unroll
        for (int it = 0; it < 16; ++it) {
            size_t i = ((size_t)vb * 16 + it) * 2048 + tid * 8;
            float4 v0 = *(const float4*)(x + i);
            float4 v1 = *(const float4*)(x + i + 4);
            union { bf16 h[8]; int4 v; } u;
            u.h[0] = __float2bfloat16(v0.x); u.h[1] = __float2bfloat16(v0.y);
            u.h[2] = __float2bfloat16(v0.z); u.h[3] = __float2bfloat16(v0.w);
            u.h[4] = __float2bfloat16(v1.x); u.h[5] = __float2bfloat16(v1.y);
            u.h[6] = __float2bfloat16(v1.z); u.h[7] = __float2bfloat16(v1.w);
            *(int4*)(x_bf + i) = u.v;
        }
        return;
    }

    // ---- splitk part ----
    constexpr int BK = 32, LDA = 2048, KLEN = 512, NN = 2048;
    const int sk = blockIdx.x >> 1;       // 0..1023
    const int bx = sk & 15, by = (sk >> 4) & 15, kz = sk >> 8;
    const bf16* A = Aw + kz * KLEN;
    const bf16* Bt = Btw + kz * KLEN;
    bf16* C = Cpart + (size_t)kz * NN * NN;

    const int wave = tid >> 6, lane = tid & 63;
    const int wr = wave >> 1, wc = wave & 1;
    const int mBase = by * 128, nBase = bx * 128;

    const int r0 = tid >> 2, c0 = tid & 3;
    const int r1 = (256 + tid) >> 2;

    const bf16* gA0 = A + (size_t)(mBase + r0) * LDA + c0 * 8;
    const bf16* gA1 = A + (size_t)(mBase + r1) * LDA + c0 * 8;
    const bf16* gB0 = Bt + (size_t)(nBase + r0) * LDA + c0 * 8;
    const bf16* gB1 = Bt + (size_t)(nBase + r1) * LDA + c0 * 8;

    char* lA0 = (char*)sA + (wave * 64) * 16;
    char* lA1 = (char*)sA + (256 + wave * 64) * 16;
    char* lB0 = (char*)sB + (wave * 64) * 16;
    char* lB1 = (char*)sB + (256 + wave * 64) * 16;

    f32x4 acc[4][4];
    #pragma unroll
    for (int i = 0; i < 4; ++i)
        #pragma unroll
        for (int j = 0; j < 4; ++j) acc[i][j] = (f32x4){0.f, 0.f, 0.f, 0.f};

    const int aRow = wr * 64 + (lane & 15);
    const int bRow = wc * 64 + (lane & 15);
    const int kOff = (lane >> 4) * 8;

    for (int k0 = 0; k0 < KLEN; k0 += BK) {
        LOAD_LDS16(gA0, lA0);
        LOAD_LDS16(gA1, lA1);
        LOAD_LDS16(gB0, lB0);
        LOAD_LDS16(gB1, lB1);
        gA0 += BK; gA1 += BK; gB0 += BK; gB1 += BK;
        __syncthreads();
        bf16x8 af[4], bfr[4];
        #pragma unroll
        for (int mf = 0; mf < 4; ++mf)
            af[mf] = *reinterpret_cast<const bf16x8*>(&sA[(aRow + mf * 16) * BK + kOff]);
        #pragma unroll
        for (int nf = 0; nf < 4; ++nf)
            bfr[nf] = *reinterpret_cast<const bf16x8*>(&sB[(bRow + nf * 16) * BK + kOff]);
        #pragma unroll
        for (int mf = 0; mf < 4; ++mf)
            #pragma unroll
            for (int nf = 0; nf < 4; ++nf)
                acc[mf][nf] = __builtin_amdgcn_mfma_f32_16x16x32_bf16(
                    af[mf], bfr[nf], acc[mf][nf], 0, 0, 0);
        __syncthreads();
    }

    const int cRow0 = mBase + wr * 64 + (lane >> 4) * 4;
    const int cCol0 = nBase + wc * 64 + (lane & 15);
    #pragma unroll
    for (int mf = 0; mf < 4; ++mf)
        #pragma unroll
        for (int nf = 0; nf < 4; ++nf)
            #pragma unroll
            for (int r = 0; r < 4; ++r)
                C[(size_t)(cRow0 + mf * 16 + r) * NN + cCol0 + nf * 16] =
                    __float2bfloat16(acc[mf][nf][r]);
}

// ---------------------------------------------------------------------------
// add four bf16 partials -> bf16
// ---------------------------------------------------------------------------
__global__ __launch_bounds__(256) void addcvt4(const bf16* __restrict__ p,
                                               bf16* __restrict__ out) {
    size_t i = ((size_t)blockIdx.x * 256 + threadIdx.x) * 8;
    constexpr size_t STRIDE = (size_t)2048 * 2048;
    float s[8];
    #pragma unroll
    for (int j = 0; j < 8; ++j) s[j] = 0.f;
    #pragma unroll
    for (int z = 0; z < 4; ++z) {
        union { bf16 h[8]; int4 v; } a;
        a.v = *(const int4*)(p + z * STRIDE + i);
        #pragma unroll
        for (int j = 0; j < 8; ++j) s[j] += __bfloat162float(a.h[j]);
    }
    union { bf16 h[8]; int4 v; } o;
    #pragma unroll
    for (int j = 0; j < 8; ++j) o.h[j] = __float2bfloat16(s[j]);
    *(int4*)(out + i) = o.v;
}

// ---------------------------------------------------------------------------
// Main GEMM: 256x256 tile, BK=64, 8-phase, T1..T5 + 1-phase-deep reg prefetch.
//   ds_reads for phase p+1 issued after barrier#1(p), before MFMA(p) ->
//   LDS burst overlaps MFMA burst (the m196 interleave lever).
//   Slot-crossing prefetches (p3->p4 slot1, p7->p0 slot0) sit after that
//   phase's vmcnt(6)+barrier, so staged data has landed.  Swizzle: phys
//   kc-chunk = kc ^ ((row>>1)&3), both-sides (source pre-swizzle + kcx).
// ---------------------------------------------------------------------------
#define GK 2048
#define LDS_SLOT 65536
#define LDS_BOFF 32768
#define LDS_KH 16384

__global__ __launch_bounds__(512, 2) void gemm256(const bf16* __restrict__ A,
                                                  const bf16* __restrict__ Bt,
                                                  const float* __restrict__ bias,
                                                  float* __restrict__ C) {
    __shared__ __align__(16) char lds[131072];

    const int tid = threadIdx.x;
    const int wave = tid >> 6, lane = tid & 63;
    const int l15 = lane & 15, kc = lane >> 4;
    const int wm = wave >> 2, wn = wave & 3;

    // T1: bijective XCD swizzle (512 wgs, 512%8==0)
    const int bid = blockIdx.x;
    const int swz = (bid & 7) * 64 + (bid >> 3);
    const int bm = swz >> 3, bn = swz & 7;
    const int mBase = bm * 256, nBase = bn * 256;

    // stage source (pre-swizzled): phys chunk tid -> logical chunk tid^((tid>>3)&3)
    const int c_log = tid ^ ((tid >> 3) & 3);
    const int srow = c_log >> 2, skc = c_log & 3;
    const bf16* gA = A + (size_t)(mBase + srow) * GK + skc * 8;
    const bf16* gB = Bt + (size_t)(nBase + srow) * GK + skc * 8;
    const int stgBase = wave * 1024;

    // read offsets: kcx = kc ^ ((l15>>1)&3)
    const int kcx = kc ^ ((l15 >> 1) & 3);
    const int aoff = wm * 8192 + l15 * 64 + kcx * 16;
    const int boff = LDS_BOFF + wn * 4096 + l15 * 64 + kcx * 16;

    f32x4 acc[8][4];
    #pragma unroll
    for (int i = 0; i < 8; ++i)
        #pragma unroll
        for (int j = 0; j < 4; ++j) acc[i][j] = (f32x4){0.f, 0.f, 0.f, 0.f};

    bf16x8 Aa[4], Ab[4], Ba[4], Bb[4];

#define STG(GSRC, LDSC, KT, KH) do {                                        \
    const bf16* _g = (GSRC) + (KT) * 64 + (KH) * 32;                        \
    LOAD_LDS16(_g, lds + (LDSC) + stgBase);                                 \
    LOAD_LDS16(_g + (size_t)128 * GK, lds + (LDSC) + stgBase + 8192);       \
} while (0)

#define READP(AN, BN, SLOT, KH, MH, DOB) do {                               \
    const int _rb = (SLOT) * LDS_SLOT + (KH) * LDS_KH;                      \
    _Pragma("unroll")                                                       \
    for (int _f = 0; _f < 4; ++_f)                                          \
        AN[_f] = *(const bf16x8*)(lds + _rb + aoff + (MH) * 4096 + _f * 1024); \
    if (DOB) {                                                              \
        _Pragma("unroll")                                                   \
        for (int _f = 0; _f < 4; ++_f)                                      \
            BN[_f] = *(const bf16x8*)(lds + _rb + boff + _f * 1024);        \
    }                                                                       \
} while (0)

    // prologue: slot0 complete (tile 0), then 3 regions of slot1 (tile 1)
    STG(gA, 0 * LDS_SLOT + 0, 0, 0);
    STG(gB, 0 * LDS_SLOT + LDS_BOFF + 0, 0, 0);
    STG(gA, 0 * LDS_SLOT + LDS_KH, 0, 1);
    STG(gB, 0 * LDS_SLOT + LDS_BOFF + LDS_KH, 0, 1);
    STG(gA, 1 * LDS_SLOT + 0, 1, 0);
    STG(gB, 1 * LDS_SLOT + LDS_BOFF + 0, 1, 0);
    STG(gB, 1 * LDS_SLOT + LDS_BOFF + LDS_KH, 1, 1);
    asm volatile("s_waitcnt vmcnt(6)");   // slot0's 8 loads landed
    __builtin_amdgcn_s_barrier();
    READP(Aa, Ba, 0, 0, 0, 1);            // regs for phase 0

    // PH: compute (MH) from CURA/CURB; prefetch (RS,RKH,RMH) into NXTA/NXTB;
    //     stage one freed region; vmcnt(6) only at p3/p7 (before barrier#1).
#define PH(CURA, CURB, NXTA, NXTB, MH, RS, RKH, RMH, RDOB, SGSRC, SLDS, SKT, SKH, DOVM) do { \
    STG(SGSRC, SLDS, SKT, SKH);                                             \
    if (DOVM) asm volatile("s_waitcnt vmcnt(6)");                           \
    __builtin_amdgcn_s_barrier();                                           \
    READP(NXTA, NXTB, RS, RKH, RMH, RDOB);                                  \
    __builtin_amdgcn_s_setprio(1);                                          \
    _Pragma("unroll")                                                       \
    for (int _mf = 0; _mf < 4; ++_mf)                                       \
        _Pragma("unroll")                                                   \
        for (int _nf = 0; _nf < 4; ++_nf)                                   \
            acc[(MH) * 4 + _mf][_nf] = __builtin_amdgcn_mfma_f32_16x16x32_bf16( \
                CURA[_mf], CURB[_nf], acc[(MH) * 4 + _mf][_nf], 0, 0, 0);   \
    __builtin_amdgcn_s_setprio(0);                                          \
    __builtin_amdgcn_s_barrier();                                           \
} while (0)

    // 32 K-tiles, 2 per iteration; ledger identical to round-3 (verified),
    // prefetch = next phase's compute coords. B sets: Ba p0-1, Bb p2-3,
    // Ba p4-5, Bb p6-7, wrap -> Ba (consistent).
    for (int it = 0; it < 16; ++it) {
        const int t0 = 2 * it;
        const int t1 = (t0 + 1) & 31, t2 = (t0 + 2) & 31, t3 = (t0 + 3) & 31;
        PH(Aa, Ba, Ab, Bb, 0, 0, 0, 1, 0, gA, 1 * LDS_SLOT + LDS_KH,            t1, 1, 0);
        PH(Ab, Ba, Aa, Bb, 1, 0, 1, 0, 1, gB, 0 * LDS_SLOT + LDS_BOFF,          t2, 0, 0);
        PH(Aa, Bb, Ab, Ba, 0, 0, 1, 1, 0, gA, 0 * LDS_SLOT + 0,                 t2, 0, 0);
        PH(Ab, Bb, Aa, Ba, 1, 1, 0, 0, 1, gB, 0 * LDS_SLOT + LDS_BOFF + LDS_KH, t2, 1, 1);
        PH(Aa, Ba, Ab, Bb, 0, 1, 0, 1, 0, gA, 0 * LDS_SLOT + LDS_KH,            t2, 1, 0);
        PH(Ab, Ba, Aa, Bb, 1, 1, 1, 0, 1, gB, 1 * LDS_SLOT + LDS_BOFF,          t3, 0, 0);
        PH(Aa, Bb, Ab, Ba, 0, 1, 1, 1, 0, gA, 1 * LDS_SLOT + 0,                 t3, 0, 0);
        PH(Ab, Bb, Aa, Ba, 1, 0, 0, 0, 1, gB, 1 * LDS_SLOT + LDS_BOFF + LDS_KH, t3, 1, 1);
    }

    // epilogue: C/D layout col=lane&15, row=(lane>>4)*4+reg
    const int cRow0 = mBase + wm * 128 + (lane >> 4) * 4;
    const int cCol0 = nBase + wn * 64 + l15;
    float bv[4];
    #pragma unroll
    for (int nf = 0; nf < 4; ++nf) bv[nf] = bias[cCol0 + nf * 16];
    #pragma unroll
    for (int Mf = 0; Mf < 8; ++Mf)
        #pragma unroll
        for (int nf = 0; nf < 4; ++nf)
            #pragma unroll
            for (int r = 0; r < 4; ++r)
                C[(size_t)(cRow0 + Mf * 16 + r) * GK + cCol0 + nf * 16] =
                    acc[Mf][nf][r] + bv[nf];
#undef PH
#undef READP
#undef STG
}

// ---------------------------------------------------------------------------
// launch
// ---------------------------------------------------------------------------
extern "C" void kernel_launch(void* const* d_in, const int* in_sizes, int n_in,
                              void* d_out, int out_size, void* d_ws, size_t ws_size,
                              hipStream_t stream) {
    const float* x     = (const float*)d_in[0];
    const float* w_in  = (const float*)d_in[1];
    const float* w_out = (const float*)d_in[2];
    const float* b_out = (const float*)d_in[3];
    const float* a_pad = (const float*)d_in[4];
    const float* b_pad = (const float*)d_in[5];
    float* out = (float*)d_out;

    char* ws = (char*)d_ws;
    bf16* x_bf  = (bf16*)ws;                        // 67,108,864 B
    bf16* woutb = (bf16*)(ws + (size_t)67108864);   //  8,388,608 B
    bf16* wint  = (bf16*)(ws + (size_t)75497472);   //  8,388,608 B
    bf16* mcomb = (bf16*)(ws + (size_t)83886080);   //  8,388,608 B  (ws total 92 MB)

    // split-K partials live in d_out (134 MB, fully overwritten by gemm256)
    bf16* part = (bf16*)d_out;                      // 4 x 8 MB

    // prep1: butterfly(W_out) || transpose(W_in)
    prep1<<<dim3(6144), dim3(256), 0, stream>>>(w_out, a_pad, b_pad, w_in, woutb, wint);
    // prep2: splitk M-GEMM (even blocks) || x->bf16 convert (odd blocks)
    prep2<<<dim3(2048), dim3(256), 0, stream>>>(woutb, wint, part, x, x_bf);
    addcvt4<<<dim3(NFEAT * BDIM / (256 * 8)), dim3(256), 0, stream>>>(part, mcomb);
    // out = x @ M^T + b  (8-phase 256^2 + reg prefetch)
    gemm256<<<dim3((BATCH / 256) * (NFEAT / 256)), dim3(512), 0, stream>>>(
        x_bf, mcomb, b_out, out);
}